// Round 17
// baseline (122.716 us; speedup 1.0000x reference)
//
#include <hip/hip_runtime.h>
#include <hip/hip_bf16.h>

// ---------------------------------------------------------------------------
// Sliding-window attention (B=4,S=2048,D=1024,H=16,HD=64,W=256) on gfx950.
// Pipeline: cvt(all) -> GEMM(QKV, 256x192 8-phase, FUSED epilogue: LDS
//           transpose; in-lane RoPE (+0.125 prescale on Q); Q/K col-block
//           [ch/16][8192][16]; V -> VT[bh][64][2048]) -> flash window attn
//           (2-deep pipelined staging, 4 blocks/CU) ->
//           GEMM(O-proj, 256x128 8-phase counted-vmcnt  <- R17 upgrade).
// ---------------------------------------------------------------------------

typedef __bf16 bf16_t;
typedef __attribute__((ext_vector_type(8))) __bf16 bf16x8;
typedef __attribute__((ext_vector_type(4))) __bf16 bf16x4;
typedef __attribute__((ext_vector_type(4))) float f32x4;

#define MFMA16(a, b, c) __builtin_amdgcn_mfma_f32_16x16x32_bf16((a), (b), (c), 0, 0, 0)

// async global->LDS, 16 bytes per lane. LDS dest is wave-uniform base + lane*16.
__device__ __forceinline__ void async16(const void* g, void* l) {
    __builtin_amdgcn_global_load_lds(
        (const __attribute__((address_space(1))) unsigned int*)g,
        (__attribute__((address_space(3))) unsigned int*)l, 16, 0, 0);
}

#define BAR() do { asm volatile("" ::: "memory"); __builtin_amdgcn_s_barrier(); \
                   asm volatile("" ::: "memory"); } while (0)
#define VMC(N) asm volatile("s_waitcnt vmcnt(" #N ")" ::: "memory")
#define LGKM0() asm volatile("s_waitcnt lgkmcnt(0)" ::: "memory")

// col-block stride for Q/K: [cb][8192 tokens][16 ch]
#define CBS 131072L   // 8192 * 16 elements

// ---------------------------------------------------------------------------
// Fused f32 -> bf16 convert for all 5 tensors, 8 elems/thread.
// ---------------------------------------------------------------------------
__global__ __launch_bounds__(256) void cvt_all(const float* __restrict__ x,
                                               const float* __restrict__ wq,
                                               const float* __restrict__ wk,
                                               const float* __restrict__ wv,
                                               const float* __restrict__ wo,
                                               bf16_t* __restrict__ xbf,
                                               bf16_t* __restrict__ wqkv,
                                               bf16_t* __restrict__ wobf) {
    const int blk = blockIdx.x;
    const float* s;
    bf16_t* d;
    int base;
    if (blk < 4096)      { s = x;  d = xbf;            base = blk; }
    else if (blk < 4608) { s = wq; d = wqkv;           base = blk - 4096; }
    else if (blk < 5120) { s = wk; d = wqkv + 1048576; base = blk - 4608; }
    else if (blk < 5632) { s = wv; d = wqkv + 2097152; base = blk - 5120; }
    else                 { s = wo; d = wobf;           base = blk - 5632; }
    const int i = (base * 256 + threadIdx.x) * 8;
    float4 a = *(const float4*)(s + i);
    float4 b = *(const float4*)(s + i + 4);
    bf16x8 o;
    o[0] = (bf16_t)a.x; o[1] = (bf16_t)a.y; o[2] = (bf16_t)a.z; o[3] = (bf16_t)a.w;
    o[4] = (bf16_t)b.x; o[5] = (bf16_t)b.y; o[6] = (bf16_t)b.z; o[7] = (bf16_t)b.w;
    *(bf16x8*)(d + i) = o;
}

// ---------------------------------------------------------------------------
// 256x192 8-phase QKV GEMM with FUSED epilogue (R14 best; unchanged).
// ---------------------------------------------------------------------------
__global__ __launch_bounds__(512, 1) __attribute__((amdgpu_waves_per_eu(2)))
void gemm192_qkv(const bf16_t* __restrict__ A, const bf16_t* __restrict__ Bw,
                 const float* __restrict__ fcos, const float* __restrict__ fsin,
                 bf16_t* __restrict__ Qo, bf16_t* __restrict__ Ko,
                 bf16_t* __restrict__ VT, int M, int N, int K) {
    __shared__ __attribute__((aligned(16))) bf16_t As[32768];   // 2 x 4u x 8KiB
    __shared__ __attribute__((aligned(16))) bf16_t Bs[24576];   // 2 x 3u x 8KiB
    const int tid = threadIdx.x;
    const int l = tid & 63, w = tid >> 6;
    const int lr = l & 15, lg = l >> 4;
    const int wr = w >> 2, wc = w & 3;          // 2M x 4N

    const int nwg = gridDim.x * gridDim.y;
    const int flat = blockIdx.y * gridDim.x + blockIdx.x;
    const int swz = (flat & 7) * (nwg >> 3) + (flat >> 3);
    const int bx = swz % gridDim.x, by = swz / gridDim.x;
    const long m0 = (long)by * 256, n0 = (long)bx * 192;
    const int NT = K >> 6;
    const int NI = NT >> 1;

    const int p  = w * 1024 + l * 16;
    const int pp = p ^ (((p >> 9) & 1) << 5);
    const int st = pp >> 10;
    const int rSt = (st >> 1) * 16 + ((pp >> 6) & 15);
    const int cSt = (st & 1) * 32 + ((pp >> 4) & 3) * 8;
    const bf16_t* aS = A  + (m0 + rSt) * K + cSt;
    const bf16_t* bS = Bw + (n0 + rSt) * K + cSt;
    const long uK = 64L * K;

    auto stageA = [&](int b, int u, int t) {
        async16(aS + (long)u * uK + (long)t * 64,
                (char*)As + b * 32768 + u * 8192 + w * 1024);
    };
    auto stageB = [&](int b, int u, int t) {
        async16(bS + (long)u * uK + (long)t * 64,
                (char*)Bs + b * 24576 + u * 8192 + w * 1024);
    };

    f32x4 acc[8][3] = {};
    bf16x8 afX[4], afY[4], bfX[3], bfY[3];
    const int swd = (lr & 8) << 2;

    auto loadAF = [&](int b, int mh, int ks, bf16x8 (&dst)[4]) {
#pragma unroll
        for (int mi = 0; mi < 4; ++mi) {
            const int off = (wr * 2 + mh) * 8192 + (mi * 2 + ks) * 1024 +
                            lr * 64 + lg * 16;
            dst[mi] = *(const bf16x8*)((const char*)As + b * 32768 + (off ^ swd));
        }
    };
    auto loadBF = [&](int b, int ks, bf16x8 (&dst)[3]) {
#pragma unroll
        for (int nj = 0; nj < 3; ++nj) {
            const int rg = wc * 48 + nj * 16 + lr;
            const int off = (rg >> 6) * 8192 + (((rg >> 4) & 3) * 2 + ks) * 1024 +
                            lr * 64 + lg * 16;
            dst[nj] = *(const bf16x8*)((const char*)Bs + b * 24576 + (off ^ swd));
        }
    };

#define QMM(MH, AF, BF) do {                                                   \
    __builtin_amdgcn_s_setprio(1);                                             \
    _Pragma("unroll")                                                          \
    for (int mi = 0; mi < 4; ++mi)                                             \
        _Pragma("unroll")                                                      \
        for (int nj = 0; nj < 3; ++nj)                                         \
            acc[(MH)*4+mi][nj] = MFMA16((AF)[mi], (BF)[nj], acc[(MH)*4+mi][nj]); \
    __builtin_amdgcn_s_setprio(0);                                             \
} while (0)

    // ---- prologue ----
    stageA(0, 0, 0); stageA(0, 1, 0); stageA(0, 2, 0); stageA(0, 3, 0);
    stageB(0, 0, 0); stageB(0, 1, 0); stageB(0, 2, 0);
    stageB(1, 0, 1); stageB(1, 1, 1); stageB(1, 2, 1);
    VMC(3);
    BAR();

#pragma unroll 1
    for (int it = 0; it < NI - 1; ++it) {
        const int T = 2 * it;
        loadAF(0, 0, 0, afX); loadBF(0, 0, bfX);
        stageA(1, 0, T + 1); stageA(1, 1, T + 1);
        BAR(); QMM(0, afX, bfX); BAR();
        loadAF(0, 1, 0, afY);
        stageA(1, 2, T + 1); stageA(1, 3, T + 1);
        BAR(); QMM(1, afY, bfX); BAR();
        loadAF(0, 0, 1, afX); loadBF(0, 1, bfY);
        BAR(); QMM(0, afX, bfY); BAR();
        loadAF(0, 1, 1, afY);
        stageB(0, 0, T + 2);
        BAR(); QMM(1, afY, bfY); VMC(1); BAR();
        loadAF(1, 0, 0, afX); loadBF(1, 0, bfX);
        stageB(0, 1, T + 2); stageB(0, 2, T + 2);
        BAR(); QMM(0, afX, bfX); BAR();
        loadAF(1, 1, 0, afY);
        stageA(0, 0, T + 2); stageA(0, 1, T + 2);
        BAR(); QMM(1, afY, bfX); BAR();
        loadAF(1, 0, 1, afX); loadBF(1, 1, bfY);
        stageA(0, 2, T + 2); stageA(0, 3, T + 2);
        BAR(); QMM(0, afX, bfY); BAR();
        loadAF(1, 1, 1, afY);
        stageB(1, 0, T + 3); stageB(1, 1, T + 3); stageB(1, 2, T + 3);
        BAR(); QMM(1, afY, bfY); VMC(3); BAR();
    }

    // ---- final iteration (tiles NT-2 buf0, NT-1 buf1) ----
    {
        loadAF(0, 0, 0, afX); loadBF(0, 0, bfX);
        stageA(1, 0, NT - 1); stageA(1, 1, NT - 1);
        BAR(); QMM(0, afX, bfX); BAR();
        loadAF(0, 1, 0, afY);
        stageA(1, 2, NT - 1); stageA(1, 3, NT - 1);
        BAR(); QMM(1, afY, bfX); BAR();
        loadAF(0, 0, 1, afX); loadBF(0, 1, bfY);
        BAR(); QMM(0, afX, bfY); BAR();
        loadAF(0, 1, 1, afY);
        BAR(); QMM(1, afY, bfY);
        VMC(0); BAR();                 // <- after this, buf0 of As/Bs is free
        loadAF(1, 0, 0, afX); loadBF(1, 0, bfX);
        QMM(0, afX, bfX);
        loadAF(1, 1, 0, afY);
        QMM(1, afY, bfX);
        loadAF(1, 0, 1, afX); loadBF(1, 1, bfY);
        QMM(0, afX, bfY);
        loadAF(1, 1, 1, afY);
        QMM(1, afY, bfY);
    }
#undef QMM

    // ---- FUSED epilogue ----
    bf16_t* scr = (w < 6) ? (bf16_t*)((char*)As + w * 5120)
                          : (bf16_t*)((char*)Bs + (w - 6) * 5120);
    asm volatile("" ::: "memory");

    const int tl = l & 31, cg = l >> 5;          // readback lane mapping
    const int chb = cg * 8;                      // channel group base 0/8

#pragma unroll
    for (int nj = 0; nj < 3; ++nj) {
        const int cbase = (int)n0 + wc * 48 + nj * 16;   // multiple of 16
        const int cls = cbase >> 10;                     // 0=q,1=k,2=v (uniform)

        // transpose this fragment: scr[token][channel] (bf16, stride 20)
#pragma unroll
        for (int ai = 0; ai < 8; ++ai)
#pragma unroll
            for (int j = 0; j < 4; ++j)
                scr[(ai * 16 + lg * 4 + j) * 20 + lr] = (bf16_t)acc[ai][nj][j];
        LGKM0();
        asm volatile("" ::: "memory");

        if (cls == 2) {
            // ---- V: within-8 key perm readback -> VT, 64B-line friendly ----
            const int ch = l >> 2;                       // channel 0..15
            const int sub = l & 3;                       // 16B chunk within 64B
            const int d16 = cbase - 2048 + ch;
            const int hh = d16 >> 6, dd = d16 & 63;
            const long T0 = m0 + wr * 128;
            const int bb = (int)(T0 >> 11);
            const int s0 = (int)(T0 & 2047);
            bf16_t* vrow = VT + ((long)((bb * 16 + hh) * 64 + dd) * 2048) + s0;
#pragma unroll
            for (int qq = 0; qq < 4; ++qq) {
                const int tb8 = qq * 32 + sub * 8;       // token base of chunk
                bf16x8 o;
#pragma unroll
                for (int j = 0; j < 8; ++j) {
                    const int f = ((j & 3) << 1) | (j >> 2);  // pos j holds key f
                    o[j] = scr[(tb8 + f) * 20 + ch];
                }
                *(bf16x8*)(vrow + tb8) = o;
            }
        } else {
            // ---- Q/K: in-lane RoPE; COL-BLOCK store (dense 1KB/wave) ----
            const int cq = cbase & 1023;
            const float sc = (cls == 0) ? 0.125f : 1.f;
            bf16_t* qk = ((cls == 0) ? Qo : Ko) + (long)(cq >> 4) * CBS + chb;
            const int p2b = ((cbase & 63) >> 1) + cg * 4;  // 4-aligned
#pragma unroll
            for (int qq = 0; qq < 4; ++qq) {
                const int t = tl + qq * 32;              // token 0..127
                bf16x4 vlo = *(const bf16x4*)&scr[t * 20 + chb];
                bf16x4 vhi = *(const bf16x4*)&scr[t * 20 + chb + 4];
                const long gt = m0 + wr * 128 + t;
                const int s0 = (int)(gt & 2047);
                const float4 cc = *(const float4*)(fcos + s0 * 32 + p2b);
                const float4 sn = *(const float4*)(fsin + s0 * 32 + p2b);
                bf16x8 o;
                float e0, e1;
                e0 = (float)vlo[0]; e1 = (float)vlo[1];
                o[0] = (bf16_t)((e0 * cc.x - e1 * sn.x) * sc);
                o[1] = (bf16_t)((e0 * sn.x + e1 * cc.x) * sc);
                e0 = (float)vlo[2]; e1 = (float)vlo[3];
                o[2] = (bf16_t)((e0 * cc.y - e1 * sn.y) * sc);
                o[3] = (bf16_t)((e0 * sn.y + e1 * cc.y) * sc);
                e0 = (float)vhi[0]; e1 = (float)vhi[1];
                o[4] = (bf16_t)((e0 * cc.z - e1 * sn.z) * sc);
                o[5] = (bf16_t)((e0 * sn.z + e1 * cc.z) * sc);
                e0 = (float)vhi[2]; e1 = (float)vhi[3];
                o[6] = (bf16_t)((e0 * cc.w - e1 * sn.w) * sc);
                o[7] = (bf16_t)((e0 * sn.w + e1 * cc.w) * sc);
                *(bf16x8*)(qk + gt * 16) = o;
            }
        }
        LGKM0();                       // all reads of scr done before reuse
        asm volatile("" ::: "memory");
    }
}

// ---------------------------------------------------------------------------
// 256x128 8-phase O-proj GEMM (R17): direct port of gemm192's counted-vmcnt
// schedule to N=128.  8 waves (2M x 4N); per-wave C = 128x32 (acc = 64).
// LDS 96 KiB: A = 2buf x 4units, B = 2buf x 2units (unit = 64x64 = 8 KiB,
// one gload_lds/thread).  6 loads/tile.  FIFO: both B(T+2) stages at P4
// (after P3's barrier -- bfY reads buf0 at P3), both B(T+3) at P8;
// VMC(2) at P4 certifies T+1 (drain oldest 6 of 8), VMC(2) at P8
// certifies T+2.  Race-freedom mirrors gemm192 phase-for-phase.
// ---------------------------------------------------------------------------
__global__ __launch_bounds__(512, 1) __attribute__((amdgpu_waves_per_eu(2)))
void gemm128_o(const bf16_t* __restrict__ A, const bf16_t* __restrict__ Bw,
               float* __restrict__ C, int M, int N, int K) {
    __shared__ __attribute__((aligned(16))) bf16_t As[32768];   // 2 x 4u x 8KiB
    __shared__ __attribute__((aligned(16))) bf16_t Bs[16384];   // 2 x 2u x 8KiB
    const int tid = threadIdx.x;
    const int l = tid & 63, w = tid >> 6;
    const int lr = l & 15, lg = l >> 4;
    const int wr = w >> 2, wc = w & 3;          // 2M x 4N

    const int nwg = gridDim.x * gridDim.y;
    const int flat = blockIdx.y * gridDim.x + blockIdx.x;
    const int swz = (flat & 7) * (nwg >> 3) + (flat >> 3);
    const int bx = swz % gridDim.x, by = swz / gridDim.x;
    const long m0 = (long)by * 256, n0 = (long)bx * 128;
    const int NT = K >> 6;
    const int NI = NT >> 1;

    const int p  = w * 1024 + l * 16;
    const int pp = p ^ (((p >> 9) & 1) << 5);
    const int st = pp >> 10;
    const int rSt = (st >> 1) * 16 + ((pp >> 6) & 15);
    const int cSt = (st & 1) * 32 + ((pp >> 4) & 3) * 8;
    const bf16_t* aS = A  + (m0 + rSt) * K + cSt;
    const bf16_t* bS = Bw + (n0 + rSt) * K + cSt;
    const long uK = 64L * K;

    auto stageA = [&](int b, int u, int t) {
        async16(aS + (long)u * uK + (long)t * 64,
                (char*)As + b * 32768 + u * 8192 + w * 1024);
    };
    auto stageB = [&](int b, int u, int t) {
        async16(bS + (long)u * uK + (long)t * 64,
                (char*)Bs + b * 16384 + u * 8192 + w * 1024);
    };

    f32x4 acc[8][2] = {};
    bf16x8 afX[4], afY[4], bfX[2], bfY[2];
    const int swd = (lr & 8) << 2;

    auto loadAF = [&](int b, int mh, int ks, bf16x8 (&dst)[4]) {
#pragma unroll
        for (int mi = 0; mi < 4; ++mi) {
            const int off = (wr * 2 + mh) * 8192 + (mi * 2 + ks) * 1024 +
                            lr * 64 + lg * 16;
            dst[mi] = *(const bf16x8*)((const char*)As + b * 32768 + (off ^ swd));
        }
    };
    auto loadBF = [&](int b, int ks, bf16x8 (&dst)[2]) {
#pragma unroll
        for (int nj = 0; nj < 2; ++nj) {
            const int rg = wc * 32 + nj * 16 + lr;       // output col 0..127
            const int off = (rg >> 6) * 8192 + (((rg >> 4) & 3) * 2 + ks) * 1024 +
                            lr * 64 + lg * 16;
            dst[nj] = *(const bf16x8*)((const char*)Bs + b * 16384 + (off ^ swd));
        }
    };

#define QMM(MH, AF, BF) do {                                                   \
    __builtin_amdgcn_s_setprio(1);                                             \
    _Pragma("unroll")                                                          \
    for (int mi = 0; mi < 4; ++mi)                                             \
        _Pragma("unroll")                                                      \
        for (int nj = 0; nj < 2; ++nj)                                         \
            acc[(MH)*4+mi][nj] = MFMA16((AF)[mi], (BF)[nj], acc[(MH)*4+mi][nj]); \
    __builtin_amdgcn_s_setprio(0);                                             \
} while (0)

    // ---- prologue: tile0 (A 4u + B 2u), then B(1) 2u; certify tile0 ----
    stageA(0, 0, 0); stageA(0, 1, 0); stageA(0, 2, 0); stageA(0, 3, 0);
    stageB(0, 0, 0); stageB(0, 1, 0);
    stageB(1, 0, 1); stageB(1, 1, 1);
    VMC(2);          // drain tile0's 6, keep B(1)'s 2
    BAR();

#pragma unroll 1
    for (int it = 0; it < NI - 1; ++it) {
        const int T = 2 * it;
        // P1 (tile T, mh0, ks0)
        loadAF(0, 0, 0, afX); loadBF(0, 0, bfX);
        stageA(1, 0, T + 1); stageA(1, 1, T + 1);
        BAR(); QMM(0, afX, bfX); BAR();
        // P2 (mh1, ks0)
        loadAF(0, 1, 0, afY);
        stageA(1, 2, T + 1); stageA(1, 3, T + 1);
        BAR(); QMM(1, afY, bfX); BAR();
        // P3 (mh0, ks1) -- no stage (bfY reads buf0 B this phase)
        loadAF(0, 0, 1, afX); loadBF(0, 1, bfY);
        BAR(); QMM(0, afX, bfY); BAR();
        // P4 (mh1, ks1): stage both B(T+2); certify tile T+1
        loadAF(0, 1, 1, afY);
        stageB(0, 0, T + 2); stageB(0, 1, T + 2);
        BAR(); QMM(1, afY, bfY); VMC(2); BAR();
        // P5 (tile T+1, mh0, ks0)
        loadAF(1, 0, 0, afX); loadBF(1, 0, bfX);
        stageA(0, 0, T + 2); stageA(0, 1, T + 2);
        BAR(); QMM(0, afX, bfX); BAR();
        // P6 (mh1, ks0)
        loadAF(1, 1, 0, afY);
        stageA(0, 2, T + 2); stageA(0, 3, T + 2);
        BAR(); QMM(1, afY, bfX); BAR();
        // P7 (mh0, ks1) -- no stage
        loadAF(1, 0, 1, afX); loadBF(1, 1, bfY);
        BAR(); QMM(0, afX, bfY); BAR();
        // P8 (mh1, ks1): stage both B(T+3); certify tile T+2
        loadAF(1, 1, 1, afY);
        stageB(1, 0, T + 3); stageB(1, 1, T + 3);
        BAR(); QMM(1, afY, bfY); VMC(2); BAR();
    }

    // ---- final iteration (tiles NT-2 buf0, NT-1 buf1) ----
    {
        loadAF(0, 0, 0, afX); loadBF(0, 0, bfX);
        stageA(1, 0, NT - 1); stageA(1, 1, NT - 1);
        BAR(); QMM(0, afX, bfX); BAR();
        loadAF(0, 1, 0, afY);
        stageA(1, 2, NT - 1); stageA(1, 3, NT - 1);
        BAR(); QMM(1, afY, bfX); BAR();
        loadAF(0, 0, 1, afX); loadBF(0, 1, bfY);
        BAR(); QMM(0, afX, bfY); BAR();
        loadAF(0, 1, 1, afY);
        BAR(); QMM(1, afY, bfY);
        VMC(0); BAR();   // drain A(NT-1)[4] + B(NT-1)[2]
        // last tile: fully resident, no LDS writers -> no barriers
        loadAF(1, 0, 0, afX); loadBF(1, 0, bfX);
        QMM(0, afX, bfX);
        loadAF(1, 1, 0, afY);
        QMM(1, afY, bfX);
        loadAF(1, 0, 1, afX); loadBF(1, 1, bfY);
        QMM(0, afX, bfY);
        loadAF(1, 1, 1, afY);
        QMM(1, afY, bfY);
    }
#undef QMM

    // ---- epilogue: fragment row = lg*4+j, col = lr (fragment-inner order) ----
#pragma unroll
    for (int ai = 0; ai < 8; ++ai)
#pragma unroll
        for (int nj = 0; nj < 2; ++nj)
#pragma unroll
            for (int j = 0; j < 4; ++j) {
                long r = m0 + wr * 128 + ai * 16 + lg * 4 + j;
                long c = n0 + wc * 32 + nj * 16 + lr;
                C[r * (long)N + c] = acc[ai][nj][j];
            }
}

// ---------------------------------------------------------------------------
// Sliding-window attention v9 (R14): 2-deep pipelined K/V staging (32 KiB ->
// 4 blocks/CU); per tile: stage(u+1) -> compute(u) -> VMC(0)+BAR.
// Q/K inputs in COL-BLOCK layout [ch/16][8192][16].  Online softmax per
// 64-key tile, swapped QK^T, prescaled Q; mask specialization for qt>=4.
// ---------------------------------------------------------------------------
__global__ __launch_bounds__(256, 4) void attn_win4(const bf16_t* __restrict__ Q,
                                                    const bf16_t* __restrict__ Kb,
                                                    const bf16_t* __restrict__ VT,
                                                    bf16_t* __restrict__ Ao) {
    __shared__ __attribute__((aligned(16))) bf16_t kld[2 * 4096];
    __shared__ __attribute__((aligned(16))) bf16_t vld[2 * 4096];
    const int raw = blockIdx.x;
    const int mswz = ((raw & 7) << 8) | (raw >> 3);
    const int qt = mswz & 31, bh = mswz >> 5;
    const int h = bh & 15, b = bh >> 4;
    const int l = threadIdx.x & 63, w = threadIdx.x >> 6;
    const int lr = l & 15, lg = l >> 4;
    const int q0 = qt * 64 + w * 16;
    const int q = q0 + lr;
    const int tb = qt - 4;

    const bf16_t* Qh = Q  + (long)(4 * h) * CBS + (long)(b * 2048) * 16;
    const bf16_t* Kh = Kb + (long)(4 * h) * CBS + (long)(b * 2048) * 16;
    const bf16_t* Vp = VT + (long)bh * 64 * 2048;

    auto stageT = [&](int u, int bs) {
        const int kt = tb + u;
        const int kt64 = (kt < 0 ? 0 : kt) * 64;
#pragma unroll
        for (int part = 0; part < 2; ++part) {
            const int seg = w * 2 + part;              // 1 KB segment 0..7
            const int r = seg * 8 + (l >> 3);          // row within 64-row tile
            const int sc = (l & 7) ^ ((r >> 1) & 7);   // swizzled 16B chunk
            async16(Kh + (sc >> 1) * CBS + (long)(kt64 + r) * 16 + (sc & 1) * 8,
                    (char*)kld + bs * 8192 + seg * 1024);
            async16(Vp + (long)r * 2048 + kt64 + sc * 8,
                    (char*)vld + bs * 8192 + seg * 1024);
        }
    };

    stageT(0, 0);
    const bf16x8 qb0 = *(const bf16x8*)&Qh[(lg >> 1) * CBS + (long)q * 16 + (lg & 1) * 8];
    const bf16x8 qb1 = *(const bf16x8*)&Qh[(2 + (lg >> 1)) * CBS + (long)q * 16 + (lg & 1) * 8];
    VMC(0);
    BAR();

    float mrun = -1000.f, lsum = 0.f;
    f32x4 o0 = {0.f, 0.f, 0.f, 0.f}, o1 = {0.f, 0.f, 0.f, 0.f};
    f32x4 o2 = {0.f, 0.f, 0.f, 0.f}, o3 = {0.f, 0.f, 0.f, 0.f};
    const int swv = (lr >> 1) & 7;

    const char* kbase;
    const char* vbase;
    int k0s;

#define QKCORE(HH, MM)                                                           \
        const int row_ = (HH) * 32 + 2 * lr + (MM);                              \
        const int sw_ = (row_ >> 1) & 7;                                         \
        bf16x8 k0_ = *(const bf16x8*)(kbase + row_ * 128 + ((lg ^ sw_) << 4));   \
        bf16x8 k1_ = *(const bf16x8*)(kbase + row_ * 128 + (((4 + lg) ^ sw_) << 4)); \
        f32x4 s_ = {0.f, 0.f, 0.f, 0.f};                                         \
        s_ = MFMA16(k0_, qb0, s_);                                               \
        s_ = MFMA16(k1_, qb1, s_);

#define QKF_F(DST, HH, MM)                                                       \
    f32x4 DST; { QKCORE(HH, MM)                                                  \
        const int kb_ = k0s + (HH) * 32 + (MM) + lg * 8;                         \
        DST[0] = ((kb_ >= 0) & ((unsigned)(q - kb_) < 256u))         ? s_[0] : -1e30f; \
        DST[1] = ((kb_ + 2 >= 0) & ((unsigned)(q - kb_ - 2) < 256u)) ? s_[1] : -1e30f; \
        DST[2] = ((kb_ + 4 >= 0) & ((unsigned)(q - kb_ - 4) < 256u)) ? s_[2] : -1e30f; \
        DST[3] = ((kb_ + 6 >= 0) & ((unsigned)(q - kb_ - 6) < 256u)) ? s_[3] : -1e30f; \
    }

#define QKF_U(DST, HH, MM)                                                       \
    f32x4 DST; { QKCORE(HH, MM)                                                  \
        const int d_ = q - (k0s + (HH) * 32 + (MM) + lg * 8);                    \
        DST[0] = (d_ < 256)     ? s_[0] : -1e30f;                                \
        DST[1] = (d_ - 2 < 256) ? s_[1] : -1e30f;                                \
        DST[2] = (d_ - 4 < 256) ? s_[2] : -1e30f;                                \
        DST[3] = (d_ - 6 < 256) ? s_[3] : -1e30f;                                \
    }

#define QKF_L(DST, HH, MM)                                                       \
    f32x4 DST; { QKCORE(HH, MM)                                                  \
        const int d_ = q - (k0s + (HH) * 32 + (MM) + lg * 8);                    \
        DST[0] = (d_ >= 0)     ? s_[0] : -1e30f;                                 \
        DST[1] = (d_ - 2 >= 0) ? s_[1] : -1e30f;                                 \
        DST[2] = (d_ - 4 >= 0) ? s_[2] : -1e30f;                                 \
        DST[3] = (d_ - 6 >= 0) ? s_[3] : -1e30f;                                 \
    }

#define QKF_N(DST, HH, MM)                                                       \
    f32x4 DST; { QKCORE(HH, MM)                                                  \
        DST[0] = s_[0]; DST[1] = s_[1]; DST[2] = s_[2]; DST[3] = s_[3];          \
    }

#define EXV(S_) {                                                                \
        S_[0] = __expf(S_[0] - mnew); S_[1] = __expf(S_[1] - mnew);              \
        S_[2] = __expf(S_[2] - mnew); S_[3] = __expf(S_[3] - mnew);              \
        rs += (S_[0] + S_[1]) + (S_[2] + S_[3]); }

#define PVF(NT, HH, PB) {                                                        \
        bf16x8 va_ = *(const bf16x8*)(vbase + ((NT) * 16 + lr) * 128 +           \
                                      ((((HH) * 4 + lg) ^ swv) << 4));           \
        o##NT = MFMA16(va_, PB, o##NT); }

#define TILEBODY(QKM) {                                                          \
        QKM(sA, 0, 0) QKM(sB, 0, 1) QKM(sC, 1, 0) QKM(sD, 1, 1)                  \
        float tm = fmaxf(fmaxf(fmaxf(sA[0], sA[1]), fmaxf(sA[2], sA[3])),        \
                         fmaxf(fmaxf(sB[0], sB[1]), fmaxf(sB[2], sB[3])));       \
        tm = fmaxf(tm, fmaxf(fmaxf(fmaxf(sC[0], sC[1]), fmaxf(sC[2], sC[3])),    \
                             fmaxf(fmaxf(sD[0], sD[1]), fmaxf(sD[2], sD[3]))));  \
        tm = fmaxf(tm, __shfl_xor(tm, 16));                                      \
        tm = fmaxf(tm, __shfl_xor(tm, 32));                                      \
        const float mnew = fmaxf(mrun, tm);                                      \
        const float alpha = __expf(mrun - mnew);                                 \
        mrun = mnew;                                                             \
        float rs = 0.f;                                                          \
        EXV(sA) EXV(sB) EXV(sC) EXV(sD)                                          \
        rs += __shfl_xor(rs, 16);                                                \
        rs += __shfl_xor(rs, 32);                                                \
        lsum = lsum * alpha + rs;                                                \
        o0[0] *= alpha; o0[1] *= alpha; o0[2] *= alpha; o0[3] *= alpha;          \
        o1[0] *= alpha; o1[1] *= alpha; o1[2] *= alpha; o1[3] *= alpha;          \
        o2[0] *= alpha; o2[1] *= alpha; o2[2] *= alpha; o2[3] *= alpha;          \
        o3[0] *= alpha; o3[1] *= alpha; o3[2] *= alpha; o3[3] *= alpha;          \
        bf16x8 pb0, pb1;                                                         \
        pb0[0] = (bf16_t)sA[0]; pb0[1] = (bf16_t)sA[1]; pb0[2] = (bf16_t)sA[2]; pb0[3] = (bf16_t)sA[3]; \
        pb0[4] = (bf16_t)sB[0]; pb0[5] = (bf16_t)sB[1]; pb0[6] = (bf16_t)sB[2]; pb0[7] = (bf16_t)sB[3]; \
        pb1[0] = (bf16_t)sC[0]; pb1[1] = (bf16_t)sC[1]; pb1[2] = (bf16_t)sC[2]; pb1[3] = (bf16_t)sC[3]; \
        pb1[4] = (bf16_t)sD[0]; pb1[5] = (bf16_t)sD[1]; pb1[6] = (bf16_t)sD[2]; pb1[7] = (bf16_t)sD[3]; \
        PVF(0, 0, pb0) PVF(1, 0, pb0) PVF(2, 0, pb0) PVF(3, 0, pb0)              \
        PVF(0, 1, pb1) PVF(1, 1, pb1) PVF(2, 1, pb1) PVF(3, 1, pb1)              \
    }

#define ITER(U, QKM) {                                                           \
        if ((U) < 4) stageT((U) + 1, ((U) + 1) & 1);                             \
        kbase = (const char*)kld + ((U) & 1) * 8192;                             \
        vbase = (const char*)vld + ((U) & 1) * 8192;                             \
        k0s = (tb + (U)) * 64;                                                   \
        TILEBODY(QKM)                                                            \
        if ((U) < 4) { VMC(0); BAR(); }                                          \
    }

    if (qt >= 4) {
        ITER(0, QKF_U)
        ITER(1, QKF_N)
        ITER(2, QKF_N)
        ITER(3, QKF_N)
        ITER(4, QKF_L)
    } else {
        ITER(0, QKF_F)
        ITER(1, QKF_F)
        ITER(2, QKF_F)
        ITER(3, QKF_F)
        ITER(4, QKF_F)
    }
#undef ITER
#undef TILEBODY
#undef QKF_F
#undef QKF_U
#undef QKF_L
#undef QKF_N
#undef QKCORE
#undef EXV
#undef PVF

    const float rinv = 1.0f / lsum;
    bf16_t* aor = Ao + ((long)(b * 2048) + q) * 1024 + h * 64;
#define EPI(NT, OA_) {                                                           \
        bf16x4 ov_;                                                             \
        ov_[0] = (bf16_t)(OA_[0] * rinv); ov_[1] = (bf16_t)(OA_[1] * rinv);      \
        ov_[2] = (bf16_t)(OA_[2] * rinv); ov_[3] = (bf16_t)(OA_[3] * rinv);      \
        *(bf16x4*)(aor + (NT) * 16 + lg * 4) = ov_; }
    EPI(0, o0) EPI(1, o1) EPI(2, o2) EPI(3, o3)
#undef EPI
}

// ---------------------------------------------------------------------------
extern "C" void kernel_launch(void* const* d_in, const int* in_sizes, int n_in,
                              void* d_out, int out_size, void* d_ws, size_t ws_size,
                              hipStream_t stream) {
    (void)in_sizes; (void)n_in; (void)out_size; (void)ws_size;
    const float* x    = (const float*)d_in[0];
    const float* fcos = (const float*)d_in[1];
    const float* fsin = (const float*)d_in[2];
    const float* wq   = (const float*)d_in[3];
    const float* wk   = (const float*)d_in[4];
    const float* wv   = (const float*)d_in[5];
    const float* wo   = (const float*)d_in[6];
    float* out = (float*)d_out;

    char* ws = (char*)d_ws;
    // layout (bytes): xbf 16MB @0 | wqkv 6MB @16M | wobf 2MB @22M |
    //                 qbuf 16MB @40M | kbuf 16MB @72M | vtb 16MB @88M.
    //                 aob reuses xbf (dead after gemm192_qkv).
    bf16_t* xbf   = (bf16_t*)(ws);
    bf16_t* wqkv  = (bf16_t*)(ws + 16777216);
    bf16_t* wobf  = (bf16_t*)(ws + 23068672);
    bf16_t* qbuf  = (bf16_t*)(ws + 41943040);
    bf16_t* kbuf  = (bf16_t*)(ws + 75497472);
    bf16_t* vtb   = (bf16_t*)(ws + 92274688);
    bf16_t* aob   = xbf;   // xbf dead after gemm192_qkv

    cvt_all<<<6144, 256, 0, stream>>>(x, wq, wk, wv, wo, xbf, wqkv, wobf);

    // QKV + fused RoPE/layout/V-transpose: (16,32) = 512 blocks = 2 rounds
    gemm192_qkv<<<dim3(16, 32), 512, 0, stream>>>(xbf, wqkv, fcos, fsin,
                                                  qbuf, kbuf, vtb,
                                                  8192, 3072, 1024);
    attn_win4<<<2048, 256, 0, stream>>>(qbuf, kbuf, vtb, aob);
    // O-proj: grid (8, 32) = 256 blocks = 1 exact round, 8-phase schedule
    gemm128_o<<<dim3(8, 32), 512, 0, stream>>>(aob, wobf, out, 8192, 1024, 1024);
}

// Round 18
// 120.456 us; speedup vs baseline: 1.0188x; 1.0188x over previous
//
#include <hip/hip_runtime.h>
#include <hip/hip_bf16.h>

// ---------------------------------------------------------------------------
// Sliding-window attention (B=4,S=2048,D=1024,H=16,HD=64,W=256) on gfx950.
// Pipeline: cvt(all) -> GEMM(QKV, 256x192 8-phase, FUSED epilogue: LDS
//           transpose; in-lane RoPE (+0.125 prescale on Q); Q/K stored in
//           COL-BLOCK layout [ch/16][8192 tok][16ch]; V -> VT[bh][64][2048])
//           -> flash window attn (2-deep pipelined K/V staging, 4 blocks/CU)
//           -> GEMM(O-proj, 256x128 3-buffer).   (= R14/R16 best config)
// ---------------------------------------------------------------------------

typedef __bf16 bf16_t;
typedef __attribute__((ext_vector_type(8))) __bf16 bf16x8;
typedef __attribute__((ext_vector_type(4))) __bf16 bf16x4;
typedef __attribute__((ext_vector_type(4))) float f32x4;

#define MFMA16(a, b, c) __builtin_amdgcn_mfma_f32_16x16x32_bf16((a), (b), (c), 0, 0, 0)

// async global->LDS, 16 bytes per lane. LDS dest is wave-uniform base + lane*16.
__device__ __forceinline__ void async16(const void* g, void* l) {
    __builtin_amdgcn_global_load_lds(
        (const __attribute__((address_space(1))) unsigned int*)g,
        (__attribute__((address_space(3))) unsigned int*)l, 16, 0, 0);
}

#define BAR() do { asm volatile("" ::: "memory"); __builtin_amdgcn_s_barrier(); \
                   asm volatile("" ::: "memory"); } while (0)
#define VMC(N) asm volatile("s_waitcnt vmcnt(" #N ")" ::: "memory")
#define LGKM0() asm volatile("s_waitcnt lgkmcnt(0)" ::: "memory")

// col-block stride for Q/K: [cb][8192 tokens][16 ch]
#define CBS 131072L   // 8192 * 16 elements

// ---------------------------------------------------------------------------
// Fused f32 -> bf16 convert for all 5 tensors, 8 elems/thread.
// ---------------------------------------------------------------------------
__global__ __launch_bounds__(256) void cvt_all(const float* __restrict__ x,
                                               const float* __restrict__ wq,
                                               const float* __restrict__ wk,
                                               const float* __restrict__ wv,
                                               const float* __restrict__ wo,
                                               bf16_t* __restrict__ xbf,
                                               bf16_t* __restrict__ wqkv,
                                               bf16_t* __restrict__ wobf) {
    const int blk = blockIdx.x;
    const float* s;
    bf16_t* d;
    int base;
    if (blk < 4096)      { s = x;  d = xbf;            base = blk; }
    else if (blk < 4608) { s = wq; d = wqkv;           base = blk - 4096; }
    else if (blk < 5120) { s = wk; d = wqkv + 1048576; base = blk - 4608; }
    else if (blk < 5632) { s = wv; d = wqkv + 2097152; base = blk - 5120; }
    else                 { s = wo; d = wobf;           base = blk - 5632; }
    const int i = (base * 256 + threadIdx.x) * 8;
    float4 a = *(const float4*)(s + i);
    float4 b = *(const float4*)(s + i + 4);
    bf16x8 o;
    o[0] = (bf16_t)a.x; o[1] = (bf16_t)a.y; o[2] = (bf16_t)a.z; o[3] = (bf16_t)a.w;
    o[4] = (bf16_t)b.x; o[5] = (bf16_t)b.y; o[6] = (bf16_t)b.z; o[7] = (bf16_t)b.w;
    *(bf16x8*)(d + i) = o;
}

// ---------------------------------------------------------------------------
// 256x192 8-phase QKV GEMM with FUSED epilogue (R14).
// Main loop: counted vmcnt (VMC(1)@P4, VMC(3)@P8 -- never 0), st_16x32
// swizzle, 8 waves (2M x 4N), per-wave C = 128x48 (acc = 96 regs; fits the
// unified VGPR/AGPR budget -- 256x256's 128-acc variant provably spills).
// Epilogue: per-fragment LDS transpose (scr[tok][ch], stride 20); then
//   q/k: in-lane RoPE (+0.125 prescale on q); COL-BLOCK store -- the wave's
//        64 stores cover 1024 contiguous bytes (WRITE_SIZE == ideal 49152).
//   v:   within-8 key permutation readback -> VT[bh][64][2048].
// ---------------------------------------------------------------------------
__global__ __launch_bounds__(512, 1) __attribute__((amdgpu_waves_per_eu(2)))
void gemm192_qkv(const bf16_t* __restrict__ A, const bf16_t* __restrict__ Bw,
                 const float* __restrict__ fcos, const float* __restrict__ fsin,
                 bf16_t* __restrict__ Qo, bf16_t* __restrict__ Ko,
                 bf16_t* __restrict__ VT, int M, int N, int K) {
    __shared__ __attribute__((aligned(16))) bf16_t As[32768];   // 2 x 4u x 8KiB
    __shared__ __attribute__((aligned(16))) bf16_t Bs[24576];   // 2 x 3u x 8KiB
    const int tid = threadIdx.x;
    const int l = tid & 63, w = tid >> 6;
    const int lr = l & 15, lg = l >> 4;
    const int wr = w >> 2, wc = w & 3;          // 2M x 4N

    const int nwg = gridDim.x * gridDim.y;
    const int flat = blockIdx.y * gridDim.x + blockIdx.x;
    const int swz = (flat & 7) * (nwg >> 3) + (flat >> 3);
    const int bx = swz % gridDim.x, by = swz / gridDim.x;
    const long m0 = (long)by * 256, n0 = (long)bx * 192;
    const int NT = K >> 6;
    const int NI = NT >> 1;

    const int p  = w * 1024 + l * 16;
    const int pp = p ^ (((p >> 9) & 1) << 5);
    const int st = pp >> 10;
    const int rSt = (st >> 1) * 16 + ((pp >> 6) & 15);
    const int cSt = (st & 1) * 32 + ((pp >> 4) & 3) * 8;
    const bf16_t* aS = A  + (m0 + rSt) * K + cSt;
    const bf16_t* bS = Bw + (n0 + rSt) * K + cSt;
    const long uK = 64L * K;

    auto stageA = [&](int b, int u, int t) {
        async16(aS + (long)u * uK + (long)t * 64,
                (char*)As + b * 32768 + u * 8192 + w * 1024);
    };
    auto stageB = [&](int b, int u, int t) {
        async16(bS + (long)u * uK + (long)t * 64,
                (char*)Bs + b * 24576 + u * 8192 + w * 1024);
    };

    f32x4 acc[8][3] = {};
    bf16x8 afX[4], afY[4], bfX[3], bfY[3];
    const int swd = (lr & 8) << 2;

    auto loadAF = [&](int b, int mh, int ks, bf16x8 (&dst)[4]) {
#pragma unroll
        for (int mi = 0; mi < 4; ++mi) {
            const int off = (wr * 2 + mh) * 8192 + (mi * 2 + ks) * 1024 +
                            lr * 64 + lg * 16;
            dst[mi] = *(const bf16x8*)((const char*)As + b * 32768 + (off ^ swd));
        }
    };
    auto loadBF = [&](int b, int ks, bf16x8 (&dst)[3]) {
#pragma unroll
        for (int nj = 0; nj < 3; ++nj) {
            const int rg = wc * 48 + nj * 16 + lr;
            const int off = (rg >> 6) * 8192 + (((rg >> 4) & 3) * 2 + ks) * 1024 +
                            lr * 64 + lg * 16;
            dst[nj] = *(const bf16x8*)((const char*)Bs + b * 24576 + (off ^ swd));
        }
    };

#define QMM(MH, AF, BF) do {                                                   \
    __builtin_amdgcn_s_setprio(1);                                             \
    _Pragma("unroll")                                                          \
    for (int mi = 0; mi < 4; ++mi)                                             \
        _Pragma("unroll")                                                      \
        for (int nj = 0; nj < 3; ++nj)                                         \
            acc[(MH)*4+mi][nj] = MFMA16((AF)[mi], (BF)[nj], acc[(MH)*4+mi][nj]); \
    __builtin_amdgcn_s_setprio(0);                                             \
} while (0)

    // ---- prologue ----
    stageA(0, 0, 0); stageA(0, 1, 0); stageA(0, 2, 0); stageA(0, 3, 0);
    stageB(0, 0, 0); stageB(0, 1, 0); stageB(0, 2, 0);
    stageB(1, 0, 1); stageB(1, 1, 1); stageB(1, 2, 1);
    VMC(3);
    BAR();

#pragma unroll 1
    for (int it = 0; it < NI - 1; ++it) {
        const int T = 2 * it;
        loadAF(0, 0, 0, afX); loadBF(0, 0, bfX);
        stageA(1, 0, T + 1); stageA(1, 1, T + 1);
        BAR(); QMM(0, afX, bfX); BAR();
        loadAF(0, 1, 0, afY);
        stageA(1, 2, T + 1); stageA(1, 3, T + 1);
        BAR(); QMM(1, afY, bfX); BAR();
        loadAF(0, 0, 1, afX); loadBF(0, 1, bfY);
        BAR(); QMM(0, afX, bfY); BAR();
        loadAF(0, 1, 1, afY);
        stageB(0, 0, T + 2);
        BAR(); QMM(1, afY, bfY); VMC(1); BAR();
        loadAF(1, 0, 0, afX); loadBF(1, 0, bfX);
        stageB(0, 1, T + 2); stageB(0, 2, T + 2);
        BAR(); QMM(0, afX, bfX); BAR();
        loadAF(1, 1, 0, afY);
        stageA(0, 0, T + 2); stageA(0, 1, T + 2);
        BAR(); QMM(1, afY, bfX); BAR();
        loadAF(1, 0, 1, afX); loadBF(1, 1, bfY);
        stageA(0, 2, T + 2); stageA(0, 3, T + 2);
        BAR(); QMM(0, afX, bfY); BAR();
        loadAF(1, 1, 1, afY);
        stageB(1, 0, T + 3); stageB(1, 1, T + 3); stageB(1, 2, T + 3);
        BAR(); QMM(1, afY, bfY); VMC(3); BAR();
    }

    // ---- final iteration (tiles NT-2 buf0, NT-1 buf1) ----
    {
        loadAF(0, 0, 0, afX); loadBF(0, 0, bfX);
        stageA(1, 0, NT - 1); stageA(1, 1, NT - 1);
        BAR(); QMM(0, afX, bfX); BAR();
        loadAF(0, 1, 0, afY);
        stageA(1, 2, NT - 1); stageA(1, 3, NT - 1);
        BAR(); QMM(1, afY, bfX); BAR();
        loadAF(0, 0, 1, afX); loadBF(0, 1, bfY);
        BAR(); QMM(0, afX, bfY); BAR();
        loadAF(0, 1, 1, afY);
        BAR(); QMM(1, afY, bfY);
        VMC(0); BAR();                 // <- after this, buf0 of As/Bs is free
        loadAF(1, 0, 0, afX); loadBF(1, 0, bfX);
        QMM(0, afX, bfX);
        loadAF(1, 1, 0, afY);
        QMM(1, afY, bfX);
        loadAF(1, 0, 1, afX); loadBF(1, 1, bfY);
        QMM(0, afX, bfY);
        loadAF(1, 1, 1, afY);
        QMM(1, afY, bfY);
    }
#undef QMM

    // ---- FUSED epilogue ----
    // per-wave private scratch in buf0 (free): 128 tok x 20 bf16 = 5120 B.
    bf16_t* scr = (w < 6) ? (bf16_t*)((char*)As + w * 5120)
                          : (bf16_t*)((char*)Bs + (w - 6) * 5120);
    asm volatile("" ::: "memory");

    const int tl = l & 31, cg = l >> 5;          // readback lane mapping
    const int chb = cg * 8;                      // channel group base 0/8

#pragma unroll
    for (int nj = 0; nj < 3; ++nj) {
        const int cbase = (int)n0 + wc * 48 + nj * 16;   // multiple of 16
        const int cls = cbase >> 10;                     // 0=q,1=k,2=v (uniform)

        // transpose this fragment: scr[token][channel] (bf16, stride 20)
#pragma unroll
        for (int ai = 0; ai < 8; ++ai)
#pragma unroll
            for (int j = 0; j < 4; ++j)
                scr[(ai * 16 + lg * 4 + j) * 20 + lr] = (bf16_t)acc[ai][nj][j];
        LGKM0();
        asm volatile("" ::: "memory");

        if (cls == 2) {
            // ---- V: within-8 key perm readback -> VT, 64B-line friendly ----
            const int ch = l >> 2;                       // channel 0..15
            const int sub = l & 3;                       // 16B chunk within 64B
            const int d16 = cbase - 2048 + ch;
            const int hh = d16 >> 6, dd = d16 & 63;
            const long T0 = m0 + wr * 128;
            const int bb = (int)(T0 >> 11);
            const int s0 = (int)(T0 & 2047);
            bf16_t* vrow = VT + ((long)((bb * 16 + hh) * 64 + dd) * 2048) + s0;
#pragma unroll
            for (int qq = 0; qq < 4; ++qq) {
                const int tb8 = qq * 32 + sub * 8;       // token base of chunk
                bf16x8 o;
#pragma unroll
                for (int j = 0; j < 8; ++j) {
                    const int f = ((j & 3) << 1) | (j >> 2);  // pos j holds key f
                    o[j] = scr[(tb8 + f) * 20 + ch];
                }
                *(bf16x8*)(vrow + tb8) = o;
            }
        } else {
            // ---- Q/K: in-lane RoPE; COL-BLOCK store (dense 1KB/wave) ----
            const int cq = cbase & 1023;
            const float sc = (cls == 0) ? 0.125f : 1.f;
            bf16_t* qk = ((cls == 0) ? Qo : Ko) + (long)(cq >> 4) * CBS + chb;
            const int p2b = ((cbase & 63) >> 1) + cg * 4;  // 4-aligned
#pragma unroll
            for (int qq = 0; qq < 4; ++qq) {
                const int t = tl + qq * 32;              // token 0..127
                bf16x4 vlo = *(const bf16x4*)&scr[t * 20 + chb];
                bf16x4 vhi = *(const bf16x4*)&scr[t * 20 + chb + 4];
                const long gt = m0 + wr * 128 + t;
                const int s0 = (int)(gt & 2047);
                const float4 cc = *(const float4*)(fcos + s0 * 32 + p2b);
                const float4 sn = *(const float4*)(fsin + s0 * 32 + p2b);
                bf16x8 o;
                float e0, e1;
                e0 = (float)vlo[0]; e1 = (float)vlo[1];
                o[0] = (bf16_t)((e0 * cc.x - e1 * sn.x) * sc);
                o[1] = (bf16_t)((e0 * sn.x + e1 * cc.x) * sc);
                e0 = (float)vlo[2]; e1 = (float)vlo[3];
                o[2] = (bf16_t)((e0 * cc.y - e1 * sn.y) * sc);
                o[3] = (bf16_t)((e0 * sn.y + e1 * cc.y) * sc);
                e0 = (float)vhi[0]; e1 = (float)vhi[1];
                o[4] = (bf16_t)((e0 * cc.z - e1 * sn.z) * sc);
                o[5] = (bf16_t)((e0 * sn.z + e1 * cc.z) * sc);
                e0 = (float)vhi[2]; e1 = (float)vhi[3];
                o[6] = (bf16_t)((e0 * cc.w - e1 * sn.w) * sc);
                o[7] = (bf16_t)((e0 * sn.w + e1 * cc.w) * sc);
                *(bf16x8*)(qk + gt * 16) = o;
            }
        }
        LGKM0();                       // all reads of scr done before reuse
        asm volatile("" ::: "memory");
    }
}

// ---------------------------------------------------------------------------
// 256x128 GEMM (O-proj: N=1024 -> 256 blocks = 1 exact round).
// Triple-buffered deep prefetch, counted vmcnt (R3/R4 version; R17's
// 8-phase port regressed -7% -- the deep schedule needs >=12 MFMA/phase).
// ---------------------------------------------------------------------------
template <typename OUT>
__global__ __launch_bounds__(512, 2) void gemm256(const bf16_t* __restrict__ A,
                                                  const bf16_t* __restrict__ Bw,
                                                  OUT* __restrict__ C,
                                                  int M, int N, int K) {
    __shared__ __attribute__((aligned(16))) bf16_t As[49152];   // 3 x 2 x 128x64
    __shared__ __attribute__((aligned(16))) bf16_t Bs[24576];   // 3 x 128x64
    const int tid = threadIdx.x;
    const int l = tid & 63, w = tid >> 6;
    const int lr = l & 15, lg = l >> 4;
    const int wr = w >> 1, wc = w & 1;

    const int nwg = gridDim.x * gridDim.y;
    const int flat = blockIdx.y * gridDim.x + blockIdx.x;
    const int swz = (flat & 7) * (nwg >> 3) + (flat >> 3);
    const int bx = swz % gridDim.x, by = swz / gridDim.x;
    const long m0 = (long)by * 256, n0 = (long)bx * 128;
    const int NT = K >> 6;

    int rS[2], cS[2];
#pragma unroll
    for (int i = 0; i < 2; ++i) {
        const int p  = i * 8192 + w * 1024 + l * 16;
        const int pp = p ^ (((p >> 9) & 1) << 5);
        const int st = pp >> 10;
        rS[i] = (st >> 1) * 16 + ((pp >> 6) & 15);
        cS[i] = (st & 1) * 32 + ((pp >> 4) & 3) * 8;
    }
    const bf16_t* aSrc0 = A  + (m0 + rS[0]) * K + cS[0];
    const bf16_t* aSrc1 = A  + (m0 + rS[1]) * K + cS[1];
    const bf16_t* bSrc0 = Bw + (n0 + rS[0]) * K + cS[0];
    const bf16_t* bSrc1 = Bw + (n0 + rS[1]) * K + cS[1];
    const long hK = 128L * K;

    auto stageA = [&](int b, int h, int t) {
        char* d = (char*)As + b * 32768 + h * 16384 + w * 1024;
        const long o = (long)h * hK + (long)t * 64;
        async16(aSrc0 + o, d);
        async16(aSrc1 + o, d + 8192);
    };
    auto stageB = [&](int b, int t) {
        char* d = (char*)Bs + b * 16384 + w * 1024;
        const long o = (long)t * 64;
        async16(bSrc0 + o, d);
        async16(bSrc1 + o, d + 8192);
    };

    f32x4 acc[4][4] = {};
    bf16x8 af[4][2], blo[2][2], bhi[2][2];
    const int swd = (lr & 8) << 2;

    auto loadA = [&](int b) {
#pragma unroll
        for (int mi = 0; mi < 4; ++mi)
#pragma unroll
            for (int ks = 0; ks < 2; ++ks) {
                const int ra = (wr & 1) * 64 + mi * 16 + lr;
                const int off = ((ra >> 4) * 2 + ks) * 1024 + (ra & 15) * 64 + lg * 16;
                af[mi][ks] = *(const bf16x8*)((const char*)As + b * 32768 +
                                              (wr >> 1) * 16384 + (off ^ swd));
            }
    };
    auto loadB = [&](int b, int nh, bf16x8 (&dst)[2][2]) {
#pragma unroll
        for (int nj = 0; nj < 2; ++nj)
#pragma unroll
            for (int ks = 0; ks < 2; ++ks) {
                const int rb = wc * 64 + (nh * 2 + nj) * 16 + lr;
                const int off = ((rb >> 4) * 2 + ks) * 1024 + (rb & 15) * 64 + lg * 16;
                dst[nj][ks] = *(const bf16x8*)((const char*)Bs + b * 16384 +
                                               (off ^ swd));
            }
    };

#define QMM(NH, BF) do {                                                       \
    __builtin_amdgcn_s_setprio(1);                                             \
    _Pragma("unroll")                                                          \
    for (int mi = 0; mi < 4; ++mi) {                                           \
        acc[mi][(NH)*2]   = MFMA16(af[mi][0], (BF)[0][0], acc[mi][(NH)*2]);    \
        acc[mi][(NH)*2]   = MFMA16(af[mi][1], (BF)[0][1], acc[mi][(NH)*2]);    \
        acc[mi][(NH)*2+1] = MFMA16(af[mi][0], (BF)[1][0], acc[mi][(NH)*2+1]);  \
        acc[mi][(NH)*2+1] = MFMA16(af[mi][1], (BF)[1][1], acc[mi][(NH)*2+1]);  \
    }                                                                          \
    __builtin_amdgcn_s_setprio(0);                                             \
} while (0)

    stageA(0, 0, 0); stageA(0, 1, 0); stageB(0, 0);
    stageA(1, 0, 1); stageA(1, 1, 1); stageB(1, 1);
    VMC(6);
    BAR();

    int bc = 0;
#pragma unroll 1
    for (int t = 0; t < NT - 2; ++t) {
        const int bn = (bc + 2 >= 3) ? bc - 1 : bc + 2;
        loadA(bc); loadB(bc, 0, blo); stageA(bn, 0, t + 2); stageA(bn, 1, t + 2);
        BAR(); QMM(0, blo); BAR();
        loadB(bc, 1, bhi); stageB(bn, t + 2);
        BAR(); QMM(1, bhi);
        if (t < NT - 3) { VMC(6); } else { VMC(0); }
        BAR();
        bc = (bc + 1 >= 3) ? 0 : bc + 1;
    }
    {
        loadA(bc); loadB(bc, 0, blo);
        QMM(0, blo);
        loadB(bc, 1, bhi);
        QMM(1, bhi);
        const int b2 = (bc + 1 >= 3) ? 0 : bc + 1;
        loadA(b2); loadB(b2, 0, blo);
        QMM(0, blo);
        loadB(b2, 1, bhi);
        QMM(1, bhi);
    }
#undef QMM

#pragma unroll
    for (int mi = 0; mi < 4; ++mi)
#pragma unroll
        for (int ni = 0; ni < 4; ++ni)
#pragma unroll
            for (int j = 0; j < 4; ++j) {
                long r = m0 + wr * 64 + mi * 16 + lg * 4 + j;
                long c = n0 + wc * 64 + ni * 16 + lr;
                C[r * N + c] = (OUT)acc[mi][ni][j];
            }
}

// ---------------------------------------------------------------------------
// Sliding-window attention v9 (R14): 2-deep pipelined K/V staging (32 KiB ->
// 4 blocks/CU); per tile: stage(u+1) -> compute(u) -> VMC(0)+BAR.
// Q/K inputs in COL-BLOCK layout [ch/16][8192][16].  Online softmax per
// 64-key tile, swapped QK^T, prescaled Q; mask specialization for qt>=4.
// ---------------------------------------------------------------------------
__global__ __launch_bounds__(256, 4) void attn_win4(const bf16_t* __restrict__ Q,
                                                    const bf16_t* __restrict__ Kb,
                                                    const bf16_t* __restrict__ VT,
                                                    bf16_t* __restrict__ Ao) {
    __shared__ __attribute__((aligned(16))) bf16_t kld[2 * 4096];
    __shared__ __attribute__((aligned(16))) bf16_t vld[2 * 4096];
    const int raw = blockIdx.x;
    const int mswz = ((raw & 7) << 8) | (raw >> 3);
    const int qt = mswz & 31, bh = mswz >> 5;
    const int h = bh & 15, b = bh >> 4;
    const int l = threadIdx.x & 63, w = threadIdx.x >> 6;
    const int lr = l & 15, lg = l >> 4;
    const int q0 = qt * 64 + w * 16;
    const int q = q0 + lr;
    const int tb = qt - 4;

    const bf16_t* Qh = Q  + (long)(4 * h) * CBS + (long)(b * 2048) * 16;
    const bf16_t* Kh = Kb + (long)(4 * h) * CBS + (long)(b * 2048) * 16;
    const bf16_t* Vp = VT + (long)bh * 64 * 2048;

    auto stageT = [&](int u, int bs) {
        const int kt = tb + u;
        const int kt64 = (kt < 0 ? 0 : kt) * 64;
#pragma unroll
        for (int part = 0; part < 2; ++part) {
            const int seg = w * 2 + part;              // 1 KB segment 0..7
            const int r = seg * 8 + (l >> 3);          // row within 64-row tile
            const int sc = (l & 7) ^ ((r >> 1) & 7);   // swizzled 16B chunk
            async16(Kh + (sc >> 1) * CBS + (long)(kt64 + r) * 16 + (sc & 1) * 8,
                    (char*)kld + bs * 8192 + seg * 1024);
            async16(Vp + (long)r * 2048 + kt64 + sc * 8,
                    (char*)vld + bs * 8192 + seg * 1024);
        }
    };

    stageT(0, 0);
    const bf16x8 qb0 = *(const bf16x8*)&Qh[(lg >> 1) * CBS + (long)q * 16 + (lg & 1) * 8];
    const bf16x8 qb1 = *(const bf16x8*)&Qh[(2 + (lg >> 1)) * CBS + (long)q * 16 + (lg & 1) * 8];
    VMC(0);
    BAR();

    float mrun = -1000.f, lsum = 0.f;
    f32x4 o0 = {0.f, 0.f, 0.f, 0.f}, o1 = {0.f, 0.f, 0.f, 0.f};
    f32x4 o2 = {0.f, 0.f, 0.f, 0.f}, o3 = {0.f, 0.f, 0.f, 0.f};
    const int swv = (lr >> 1) & 7;

    const char* kbase;
    const char* vbase;
    int k0s;

#define QKCORE(HH, MM)                                                           \
        const int row_ = (HH) * 32 + 2 * lr + (MM);                              \
        const int sw_ = (row_ >> 1) & 7;                                         \
        bf16x8 k0_ = *(const bf16x8*)(kbase + row_ * 128 + ((lg ^ sw_) << 4));   \
        bf16x8 k1_ = *(const bf16x8*)(kbase + row_ * 128 + (((4 + lg) ^ sw_) << 4)); \
        f32x4 s_ = {0.f, 0.f, 0.f, 0.f};                                         \
        s_ = MFMA16(k0_, qb0, s_);                                               \
        s_ = MFMA16(k1_, qb1, s_);

#define QKF_F(DST, HH, MM)                                                       \
    f32x4 DST; { QKCORE(HH, MM)                                                  \
        const int kb_ = k0s + (HH) * 32 + (MM) + lg * 8;                         \
        DST[0] = ((kb_ >= 0) & ((unsigned)(q - kb_) < 256u))         ? s_[0] : -1e30f; \
        DST[1] = ((kb_ + 2 >= 0) & ((unsigned)(q - kb_ - 2) < 256u)) ? s_[1] : -1e30f; \
        DST[2] = ((kb_ + 4 >= 0) & ((unsigned)(q - kb_ - 4) < 256u)) ? s_[2] : -1e30f; \
        DST[3] = ((kb_ + 6 >= 0) & ((unsigned)(q - kb_ - 6) < 256u)) ? s_[3] : -1e30f; \
    }

#define QKF_U(DST, HH, MM)                                                       \
    f32x4 DST; { QKCORE(HH, MM)                                                  \
        const int d_ = q - (k0s + (HH) * 32 + (MM) + lg * 8);                    \
        DST[0] = (d_ < 256)     ? s_[0] : -1e30f;                                \
        DST[1] = (d_ - 2 < 256) ? s_[1] : -1e30f;                                \
        DST[2] = (d_ - 4 < 256) ? s_[2] : -1e30f;                                \
        DST[3] = (d_ - 6 < 256) ? s_[3] : -1e30f;                                \
    }

#define QKF_L(DST, HH, MM)                                                       \
    f32x4 DST; { QKCORE(HH, MM)                                                  \
        const int d_ = q - (k0s + (HH) * 32 + (MM) + lg * 8);                    \
        DST[0] = (d_ >= 0)     ? s_[0] : -1e30f;                                 \
        DST[1] = (d_ - 2 >= 0) ? s_[1] : -1e30f;                                 \
        DST[2] = (d_ - 4 >= 0) ? s_[2] : -1e30f;                                 \
        DST[3] = (d_ - 6 >= 0) ? s_[3] : -1e30f;                                 \
    }

#define QKF_N(DST, HH, MM)                                                       \
    f32x4 DST; { QKCORE(HH, MM)                                                  \
        DST[0] = s_[0]; DST[1] = s_[1]; DST[2] = s_[2]; DST[3] = s_[3];          \
    }

#define EXV(S_) {                                                                \
        S_[0] = __expf(S_[0] - mnew); S_[1] = __expf(S_[1] - mnew);              \
        S_[2] = __expf(S_[2] - mnew); S_[3] = __expf(S_[3] - mnew);              \
        rs += (S_[0] + S_[1]) + (S_[2] + S_[3]); }

#define PVF(NT, HH, PB) {                                                        \
        bf16x8 va_ = *(const bf16x8*)(vbase + ((NT) * 16 + lr) * 128 +           \
                                      ((((HH) * 4 + lg) ^ swv) << 4));           \
        o##NT = MFMA16(va_, PB, o##NT); }

#define TILEBODY(QKM) {                                                          \
        QKM(sA, 0, 0) QKM(sB, 0, 1) QKM(sC, 1, 0) QKM(sD, 1, 1)                  \
        float tm = fmaxf(fmaxf(fmaxf(sA[0], sA[1]), fmaxf(sA[2], sA[3])),        \
                         fmaxf(fmaxf(sB[0], sB[1]), fmaxf(sB[2], sB[3])));       \
        tm = fmaxf(tm, fmaxf(fmaxf(fmaxf(sC[0], sC[1]), fmaxf(sC[2], sC[3])),    \
                             fmaxf(fmaxf(sD[0], sD[1]), fmaxf(sD[2], sD[3]))));  \
        tm = fmaxf(tm, __shfl_xor(tm, 16));                                      \
        tm = fmaxf(tm, __shfl_xor(tm, 32));                                      \
        const float mnew = fmaxf(mrun, tm);                                      \
        const float alpha = __expf(mrun - mnew);                                 \
        mrun = mnew;                                                             \
        float rs = 0.f;                                                          \
        EXV(sA) EXV(sB) EXV(sC) EXV(sD)                                          \
        rs += __shfl_xor(rs, 16);                                                \
        rs += __shfl_xor(rs, 32);                                                \
        lsum = lsum * alpha + rs;                                                \
        o0[0] *= alpha; o0[1] *= alpha; o0[2] *= alpha; o0[3] *= alpha;          \
        o1[0] *= alpha; o1[1] *= alpha; o1[2] *= alpha; o1[3] *= alpha;          \
        o2[0] *= alpha; o2[1] *= alpha; o2[2] *= alpha; o2[3] *= alpha;          \
        o3[0] *= alpha; o3[1] *= alpha; o3[2] *= alpha; o3[3] *= alpha;          \
        bf16x8 pb0, pb1;                                                         \
        pb0[0] = (bf16_t)sA[0]; pb0[1] = (bf16_t)sA[1]; pb0[2] = (bf16_t)sA[2]; pb0[3] = (bf16_t)sA[3]; \
        pb0[4] = (bf16_t)sB[0]; pb0[5] = (bf16_t)sB[1]; pb0[6] = (bf16_t)sB[2]; pb0[7] = (bf16_t)sB[3]; \
        pb1[0] = (bf16_t)sC[0]; pb1[1] = (bf16_t)sC[1]; pb1[2] = (bf16_t)sC[2]; pb1[3] = (bf16_t)sC[3]; \
        pb1[4] = (bf16_t)sD[0]; pb1[5] = (bf16_t)sD[1]; pb1[6] = (bf16_t)sD[2]; pb1[7] = (bf16_t)sD[3]; \
        PVF(0, 0, pb0) PVF(1, 0, pb0) PVF(2, 0, pb0) PVF(3, 0, pb0)              \
        PVF(0, 1, pb1) PVF(1, 1, pb1) PVF(2, 1, pb1) PVF(3, 1, pb1)              \
    }

#define ITER(U, QKM) {                                                           \
        if ((U) < 4) stageT((U) + 1, ((U) + 1) & 1);                             \
        kbase = (const char*)kld + ((U) & 1) * 8192;                             \
        vbase = (const char*)vld + ((U) & 1) * 8192;                             \
        k0s = (tb + (U)) * 64;                                                   \
        TILEBODY(QKM)                                                            \
        if ((U) < 4) { VMC(0); BAR(); }                                          \
    }

    if (qt >= 4) {
        ITER(0, QKF_U)
        ITER(1, QKF_N)
        ITER(2, QKF_N)
        ITER(3, QKF_N)
        ITER(4, QKF_L)
    } else {
        ITER(0, QKF_F)
        ITER(1, QKF_F)
        ITER(2, QKF_F)
        ITER(3, QKF_F)
        ITER(4, QKF_F)
    }
#undef ITER
#undef TILEBODY
#undef QKF_F
#undef QKF_U
#undef QKF_L
#undef QKF_N
#undef QKCORE
#undef EXV
#undef PVF

    const float rinv = 1.0f / lsum;
    bf16_t* aor = Ao + ((long)(b * 2048) + q) * 1024 + h * 64;
#define EPI(NT, OA_) {                                                           \
        bf16x4 ov_;                                                             \
        ov_[0] = (bf16_t)(OA_[0] * rinv); ov_[1] = (bf16_t)(OA_[1] * rinv);      \
        ov_[2] = (bf16_t)(OA_[2] * rinv); ov_[3] = (bf16_t)(OA_[3] * rinv);      \
        *(bf16x4*)(aor + (NT) * 16 + lg * 4) = ov_; }
    EPI(0, o0) EPI(1, o1) EPI(2, o2) EPI(3, o3)
#undef EPI
}

// ---------------------------------------------------------------------------
extern "C" void kernel_launch(void* const* d_in, const int* in_sizes, int n_in,
                              void* d_out, int out_size, void* d_ws, size_t ws_size,
                              hipStream_t stream) {
    (void)in_sizes; (void)n_in; (void)out_size; (void)ws_size;
    const float* x    = (const float*)d_in[0];
    const float* fcos = (const float*)d_in[1];
    const float* fsin = (const float*)d_in[2];
    const float* wq   = (const float*)d_in[3];
    const float* wk   = (const float*)d_in[4];
    const float* wv   = (const float*)d_in[5];
    const float* wo   = (const float*)d_in[6];
    float* out = (float*)d_out;

    char* ws = (char*)d_ws;
    // layout (bytes): xbf 16MB @0 | wqkv 6MB @16M | wobf 2MB @22M |
    //                 qbuf 16MB @40M | kbuf 16MB @72M | vtb 16MB @88M.
    //                 aob reuses xbf (dead after gemm192_qkv).
    bf16_t* xbf   = (bf16_t*)(ws);
    bf16_t* wqkv  = (bf16_t*)(ws + 16777216);
    bf16_t* wobf  = (bf16_t*)(ws + 23068672);
    bf16_t* qbuf  = (bf16_t*)(ws + 41943040);
    bf16_t* kbuf  = (bf16_t*)(ws + 75497472);
    bf16_t* vtb   = (bf16_t*)(ws + 92274688);
    bf16_t* aob   = xbf;   // xbf dead after gemm192_qkv

    cvt_all<<<6144, 256, 0, stream>>>(x, wq, wk, wv, wo, xbf, wqkv, wobf);

    // QKV + fused RoPE/layout/V-transpose: (16,32) = 512 blocks = 2 rounds
    gemm192_qkv<<<dim3(16, 32), 512, 0, stream>>>(xbf, wqkv, fcos, fsin,
                                                  qbuf, kbuf, vtb,
                                                  8192, 3072, 1024);
    attn_win4<<<2048, 256, 0, stream>>>(qbuf, kbuf, vtb, aob);
    // O-proj: grid (8, 32) = 256 blocks = 1 exact round
    gemm256<float><<<dim3(8, 32), 512, 0, stream>>>(aob, wobf, out, 8192, 1024, 1024);
}